// Round 4
// baseline (1574.740 us; speedup 1.0000x reference)
//
#include <hip/hip_runtime.h>

#define NN 114688      // nodes
#define NE 917504      // edges
#define NBATCH 8192    // graphs
#define GSZ 14         // nodes per graph
#define NCLS 10
#define EPSB 1e-5f
#define NSCAN 112      // NN / 1024

typedef unsigned short u16;
typedef short bf16x8 __attribute__((ext_vector_type(8)));
typedef float f32x4 __attribute__((ext_vector_type(4)));
typedef _Float16 h2t __attribute__((ext_vector_type(2)));
typedef _Float16 h4t __attribute__((ext_vector_type(4)));

__device__ __forceinline__ float bf2f(u16 u) {
    union { unsigned int i; float f; } v; v.i = ((unsigned int)u) << 16; return v.f;
}
__device__ __forceinline__ u16 f2bf(float f) {
    union { float f; unsigned int i; } v; v.f = f;
    unsigned int i = v.i;
    unsigned int r = i + 0x7FFFu + ((i >> 16) & 1u);   // RNE
    return (u16)(r >> 16);
}

// generic vector load/store of V elements as fp32, ST in {float, _Float16}
template<typename ST, int V>
__device__ __forceinline__ void ldv(const ST* p, float* y) {
    if constexpr (V == 1) { y[0] = (float)p[0]; }
    else if constexpr (V == 2) {
        if constexpr (sizeof(ST) == 4) { float2 v = *(const float2*)p; y[0] = v.x; y[1] = v.y; }
        else { h2t v = *(const h2t*)p; y[0] = (float)v[0]; y[1] = (float)v[1]; }
    } else {
        if constexpr (sizeof(ST) == 4) { float4 v = *(const float4*)p; y[0] = v.x; y[1] = v.y; y[2] = v.z; y[3] = v.w; }
        else { h4t v = *(const h4t*)p; y[0] = (float)v[0]; y[1] = (float)v[1]; y[2] = (float)v[2]; y[3] = (float)v[3]; }
    }
}
template<typename ST, int V>
__device__ __forceinline__ void stv(ST* p, const float* y) {
    if constexpr (V == 1) { p[0] = (ST)y[0]; }
    else if constexpr (V == 2) {
        if constexpr (sizeof(ST) == 4) { float2 v; v.x = y[0]; v.y = y[1]; *(float2*)p = v; }
        else { h2t v; v[0] = (_Float16)y[0]; v[1] = (_Float16)y[1]; *(h2t*)p = v; }
    } else {
        if constexpr (sizeof(ST) == 4) { float4 v; v.x = y[0]; v.y = y[1]; v.z = y[2]; v.w = y[3]; *(float4*)p = v; }
        else { h4t v; v[0] = (_Float16)y[0]; v[1] = (_Float16)y[1]; v[2] = (_Float16)y[2]; v[3] = (_Float16)y[3]; *(h4t*)p = v; }
    }
}

// ---------------- graph preprocessing ----------------
__global__ __launch_bounds__(256) void k_hist(const int* __restrict__ ei, int* __restrict__ counts) {
    int e = blockIdx.x * 256 + threadIdx.x;
    atomicAdd(&counts[ei[NE + e]], 1);
}

__global__ __launch_bounds__(256) void k_scan1(const int* __restrict__ counts, int* __restrict__ bsum) {
    __shared__ int red[256];
    int tid = threadIdx.x;
    int base = blockIdx.x * 1024 + tid * 4;
    int s = counts[base] + counts[base + 1] + counts[base + 2] + counts[base + 3];
    red[tid] = s; __syncthreads();
    for (int o = 128; o > 0; o >>= 1) {
        if (tid < o) red[tid] += red[tid + o];
        __syncthreads();
    }
    if (tid == 0) bsum[blockIdx.x] = red[0];
}

__global__ void k_scan2(int* bsum, int* offs) {
    if (threadIdx.x == 0) {
        int run = 0;
        for (int i = 0; i < NSCAN; i++) { int t = bsum[i]; bsum[i] = run; run += t; }
        offs[NN] = run;
    }
}

__global__ __launch_bounds__(256) void k_scan3(const int* __restrict__ counts, const int* __restrict__ bsum,
                                               int* __restrict__ offs) {
    __shared__ int ss[256];
    int tid = threadIdx.x;
    int base = blockIdx.x * 1024 + tid * 4;
    int v0 = counts[base], v1 = counts[base + 1], v2 = counts[base + 2], v3 = counts[base + 3];
    int ts = v0 + v1 + v2 + v3;
    ss[tid] = ts; __syncthreads();
    for (int o = 1; o < 256; o <<= 1) {
        int add = (tid >= o) ? ss[tid - o] : 0;
        __syncthreads();
        ss[tid] += add;
        __syncthreads();
    }
    int excl = ss[tid] - ts + bsum[blockIdx.x];
    offs[base] = excl;
    offs[base + 1] = excl + v0;
    offs[base + 2] = excl + v0 + v1;
    offs[base + 3] = excl + v0 + v1 + v2;
}

__global__ __launch_bounds__(256) void k_dis_cursor(const int* __restrict__ counts, const int* __restrict__ offs,
                                                    float* __restrict__ dis, int* __restrict__ cursor) {
    int n = blockIdx.x * 256 + threadIdx.x;
    dis[n] = rsqrtf((float)counts[n] + 1.0f);
    cursor[n] = offs[n];
}

__global__ __launch_bounds__(256) void k_scatter(const int* __restrict__ ei, int* __restrict__ cursor,
                                                 int* __restrict__ srcs) {
    int e = blockIdx.x * 256 + threadIdx.x;
    int d = ei[NE + e], s = ei[e];
    int p = atomicAdd(&cursor[d], 1);
    srcs[p] = s;
}

// transpose + hi/lo-split fp32 W[K,F] -> bf16 Wh/Wl [F,K]  (Markidis split)
__global__ __launch_bounds__(256) void k_tsplit(const float* __restrict__ Wsrc,
                                                u16* __restrict__ Wh, u16* __restrict__ Wl,
                                                int K, int F) {
    int i = blockIdx.x * 256 + threadIdx.x;
    if (i < K * F) {
        int k = i / F, f = i % F;
        float w = Wsrc[i];
        u16 h = f2bf(w);
        float r = w - bf2f(h);
        Wh[f * K + k] = h;
        Wl[f * K + k] = f2bf(r);
    }
}

// ---------------- split MFMA GEMM: C = affine(A) @ W,  fp32-grade via bf16x3 ----------------
// A: AT (float or _Float16), per-channel affine optional. W pre-split bf16 hi/lo, [Fout][K].
// D = ah*wh + al*wh + ah*wl  (al*wl ~2^-16, skipped). C stored as CT.
template<int BM, int BN, int WCOLS, typename AT, typename CT, bool AFF>
__global__ __launch_bounds__(256) void k_gemm(
    const AT* __restrict__ A, const u16* __restrict__ Wh, const u16* __restrict__ Wl,
    CT* __restrict__ C, const int K, const int Fout,
    const float* __restrict__ sc, const float* __restrict__ sh)
{
    constexpr int AST = 40;                // 32 + 8 pad
    __shared__ u16 Ah[BM][AST], Al[BM][AST];
    __shared__ u16 Bh[BN][AST], Bl[BN][AST];
    __shared__ float scs[AFF ? 256 : 1], shs[AFF ? 256 : 1];

    const int tid = threadIdx.x;
    const int row0 = blockIdx.y * BM;
    const int col0 = blockIdx.x * BN;

    if constexpr (AFF) {
        for (int i = tid; i < K; i += 256) { scs[i] = sc[i]; shs[i] = sh[i]; }
    }

    const int wave = tid >> 6, lane = tid & 63;
    const int mb = (wave / WCOLS) * 64;
    const int nb = (wave % WCOLS) * 64;
    const int lm = lane & 15;
    const int lk = (lane >> 4) * 8;

    f32x4 acc[4][4];
#pragma unroll
    for (int i = 0; i < 4; i++)
#pragma unroll
        for (int j = 0; j < 4; j++)
#pragma unroll
            for (int r = 0; r < 4; r++) acc[i][j][r] = 0.f;

    const int stg_r = tid >> 3;        // 0..31
    const int stg_c = (tid & 7) * 4;   // 0,4..28

    for (int k0 = 0; k0 < K; k0 += 32) {
        __syncthreads();
#pragma unroll
        for (int p = 0; p < BM / 32; p++) {
            const int r = p * 32 + stg_r;
            float y[4];
            ldv<AT, 4>(A + (size_t)(row0 + r) * K + k0 + stg_c, y);
            ushort4 hv, lv;
#pragma unroll
            for (int q = 0; q < 4; q++) {
                float yy = y[q];
                if constexpr (AFF) yy = yy * scs[k0 + stg_c + q] + shs[k0 + stg_c + q];
                u16 h = f2bf(yy);
                float rm = yy - bf2f(h);
                ((u16*)&hv)[q] = h;
                ((u16*)&lv)[q] = f2bf(rm);
            }
            *(ushort4*)&Ah[r][stg_c] = hv;
            *(ushort4*)&Al[r][stg_c] = lv;
        }
#pragma unroll
        for (int p = 0; p < BN / 32; p++) {
            const int n = p * 32 + stg_r;
            *(ushort4*)&Bh[n][stg_c] = *(const ushort4*)(Wh + (size_t)(col0 + n) * K + k0 + stg_c);
            *(ushort4*)&Bl[n][stg_c] = *(const ushort4*)(Wl + (size_t)(col0 + n) * K + k0 + stg_c);
        }
        __syncthreads();

        bf16x8 ah[4], al[4], bh[4], bl[4];
#pragma unroll
        for (int mi = 0; mi < 4; mi++) {
            ah[mi] = *(const bf16x8*)&Ah[mb + mi * 16 + lm][lk];
            al[mi] = *(const bf16x8*)&Al[mb + mi * 16 + lm][lk];
        }
#pragma unroll
        for (int ni = 0; ni < 4; ni++) {
            bh[ni] = *(const bf16x8*)&Bh[nb + ni * 16 + lm][lk];
            bl[ni] = *(const bf16x8*)&Bl[nb + ni * 16 + lm][lk];
        }
#pragma unroll
        for (int mi = 0; mi < 4; mi++)
#pragma unroll
            for (int ni = 0; ni < 4; ni++) {
                acc[mi][ni] = __builtin_amdgcn_mfma_f32_16x16x32_bf16(al[mi], bh[ni], acc[mi][ni], 0, 0, 0);
                acc[mi][ni] = __builtin_amdgcn_mfma_f32_16x16x32_bf16(ah[mi], bl[ni], acc[mi][ni], 0, 0, 0);
                acc[mi][ni] = __builtin_amdgcn_mfma_f32_16x16x32_bf16(ah[mi], bh[ni], acc[mi][ni], 0, 0, 0);
            }
    }

    const int rb = row0 + mb + (lane >> 4) * 4;
    const int cb = col0 + nb + lm;
#pragma unroll
    for (int mi = 0; mi < 4; mi++)
#pragma unroll
        for (int ni = 0; ni < 4; ni++)
#pragma unroll
            for (int r = 0; r < 4; r++)
                C[(size_t)(rb + mi * 16 + r) * Fout + cb + ni * 16] = (CT)acc[mi][ni][r];
}

// ---------------- aggregation: t = relu(dn*sum(dis_s*h_s) + dn^2*h_n + b), fused BN stats --------
// CH channels; h row stride istr, t row stride ostr (supports channel-split layer).
template<int CH, int VPT, typename ST>
__global__ __launch_bounds__(256) void k_agg(
    const ST* __restrict__ h, ST* __restrict__ t, const float* __restrict__ bias,
    const int* __restrict__ off, const int* __restrict__ srcs,
    const float* __restrict__ dis, float* __restrict__ statS, float* __restrict__ statQ,
    const int istr, const int ostr)
{
    __shared__ float redS[CH], redQ[CH];
    const int tid = threadIdx.x;
    for (int i = tid; i < CH; i += 256) { redS[i] = 0.f; redQ[i] = 0.f; }
    __syncthreads();

    const int lane = tid & 63;
    const int c = lane * VPT;
    const bool act = (c < CH);
    const int wid = (blockIdx.x * 256 + tid) >> 6;
    const int nw = (gridDim.x * 256) >> 6;

    float bs[VPT], bq[VPT], bv[VPT];
#pragma unroll
    for (int v = 0; v < VPT; v++) { bs[v] = 0.f; bq[v] = 0.f; bv[v] = act ? bias[c + v] : 0.f; }

    for (int n = wid; n < NN; n += nw) {
        const int p0 = off[n], p1 = off[n + 1];
        if (act) {
            float a[VPT];
#pragma unroll
            for (int v = 0; v < VPT; v++) a[v] = 0.f;
            int p = p0;
            int s = 0; float w = 0.f;
            if (p < p1) { s = srcs[p]; w = dis[s]; }
            while (p < p1) {
                const int pn = p + 1;
                int s2 = 0; float w2 = 0.f;
                if (pn < p1) { s2 = srcs[pn]; w2 = dis[s2]; }   // prefetch next edge
                float hv[VPT];
                ldv<ST, VPT>(h + (size_t)s * istr + c, hv);
#pragma unroll
                for (int v = 0; v < VPT; v++) a[v] += w * hv[v];
                s = s2; w = w2; p = pn;
            }
            const float dn = dis[n];
            const float dn2 = dn * dn;
            float hn[VPT];
            ldv<ST, VPT>(h + (size_t)n * istr + c, hn);
            float o[VPT];
#pragma unroll
            for (int v = 0; v < VPT; v++) {
                float ov = fmaxf(dn * a[v] + dn2 * hn[v] + bv[v], 0.f);
                ST rv = (ST)ov;             // stats on the STORED (rounded) value
                o[v] = (float)rv;
                bs[v] += o[v]; bq[v] += o[v] * o[v];
            }
            stv<ST, VPT>(t + (size_t)n * ostr + c, o);
        }
    }
    if (act) {
#pragma unroll
        for (int v = 0; v < VPT; v++) { atomicAdd(&redS[c + v], bs[v]); atomicAdd(&redQ[c + v], bq[v]); }
    }
    __syncthreads();
    for (int i = tid; i < CH; i += 256) { atomicAdd(&statS[i], redS[i]); atomicAdd(&statQ[i], redQ[i]); }
}

// ---------------- BN stats -> scale/shift ----------------
__global__ void k_bnpar(const float* __restrict__ S, const float* __restrict__ Q,
                        const float* __restrict__ g, const float* __restrict__ b,
                        float* __restrict__ sc, float* __restrict__ sh, int F) {
    int c = threadIdx.x;
    if (c >= F) return;
    const float invn = 1.0f / (float)NN;
    float mean = S[c] * invn;
    float var = Q[c] * invn - mean * mean;
    float s = g[c] * rsqrtf(fmaxf(var, 0.f) + EPSB);
    sc[c] = s;
    sh[c] = b[c] - mean * s;
}

// ---------------- small dense layer: C[N,F] = affine(A)[N,K] @ W[K,F] (+bias), fp32 compute ------
template<int K, int F, bool BIAS, typename ST>
__global__ __launch_bounds__(256) void k_smm(
    const ST* __restrict__ A, const float* __restrict__ Wf, const float* __restrict__ bias,
    ST* __restrict__ C, const float* __restrict__ sc, const float* __restrict__ sh)
{
    __shared__ float Wl[K * F];
    __shared__ float scl[K], shl[K], bl[F];
    const int tid = threadIdx.x;
    for (int i = tid; i < K * F; i += 256) Wl[i] = Wf[i];
    if (tid < K) { scl[tid] = sc[tid]; shl[tid] = sh[tid]; }
    if (tid < F) {
        bl[tid] = 0.f;
        if constexpr (BIAS) bl[tid] = bias[tid];
    }
    __syncthreads();
    const int n = blockIdx.x * 256 + tid;
    float acc[F];
#pragma unroll
    for (int f = 0; f < F; f++) acc[f] = bl[f];
    const ST* ar = A + (size_t)n * K;
    for (int k = 0; k < K; k += 4) {
        float av[4];
        ldv<ST, 4>(ar + k, av);
        float y0 = av[0] * scl[k] + shl[k];
        float y1 = av[1] * scl[k + 1] + shl[k + 1];
        float y2 = av[2] * scl[k + 2] + shl[k + 2];
        float y3 = av[3] * scl[k + 3] + shl[k + 3];
#pragma unroll
        for (int f = 0; f < F; f += 4) {
            float4 w0 = *(const float4*)&Wl[k * F + f];
            float4 w1 = *(const float4*)&Wl[(k + 1) * F + f];
            float4 w2 = *(const float4*)&Wl[(k + 2) * F + f];
            float4 w3 = *(const float4*)&Wl[(k + 3) * F + f];
            acc[f + 0] += y0 * w0.x + y1 * w1.x + y2 * w2.x + y3 * w3.x;
            acc[f + 1] += y0 * w0.y + y1 * w1.y + y2 * w2.y + y3 * w3.y;
            acc[f + 2] += y0 * w0.z + y1 * w1.z + y2 * w2.z + y3 * w3.z;
            acc[f + 3] += y0 * w0.w + y1 * w1.w + y2 * w2.w + y3 * w3.w;
        }
    }
    ST* cr = C + (size_t)n * F;
#pragma unroll
    for (int f = 0; f < F; f++) cr[f] = (ST)acc[f];
}

// ---------------- per-channel stats over [NN, F] ----------------
template<int F, typename ST>
__global__ __launch_bounds__(256) void k_stats16(const ST* __restrict__ A,
                                                 float* __restrict__ S, float* __restrict__ Q) {
    __shared__ float redS[F], redQ[F];
    const int tid = threadIdx.x;
    for (int i = tid; i < F; i += 256) { redS[i] = 0.f; redQ[i] = 0.f; }
    __syncthreads();
    const int g = blockIdx.x * 256 + tid;
    const int c = g % F;
    const int step = (gridDim.x * 256) / F;
    float s = 0.f, q = 0.f;
    for (int r = g / F; r < NN; r += step) {
        float v = (float)A[(size_t)r * F + c];
        s += v; q += v * v;
    }
    atomicAdd(&redS[c], s); atomicAdd(&redQ[c], q);
    __syncthreads();
    for (int i = tid; i < F; i += 256) { atomicAdd(&S[i], redS[i]); atomicAdd(&Q[i], redQ[i]); }
}

// stats over fp32 [NN] vector
__global__ __launch_bounds__(256) void k_stats1(const float* __restrict__ A,
                                                float* __restrict__ S, float* __restrict__ Q) {
    __shared__ float redS[1], redQ[1];
    const int tid = threadIdx.x;
    if (tid == 0) { redS[0] = 0.f; redQ[0] = 0.f; }
    __syncthreads();
    const int g = blockIdx.x * 256 + tid;
    const int step = gridDim.x * 256;
    float s = 0.f, q = 0.f;
    for (int r = g; r < NN; r += step) {
        float v = A[r];
        s += v; q += v * v;
    }
    atomicAdd(&redS[0], s); atomicAdd(&redQ[0], q);
    __syncthreads();
    if (tid == 0) { atomicAdd(&S[0], redS[0]); atomicAdd(&Q[0], redQ[0]); }
}

// ---------------- gate layer 2: g2 = relu(bn1(g1)) @ gW2 + gb2 ----------------
template<typename ST>
__global__ __launch_bounds__(256) void k_gate2(const ST* __restrict__ g1,
                                               const float* __restrict__ sc, const float* __restrict__ sh,
                                               const float* __restrict__ w2, const float* __restrict__ b2,
                                               float* __restrict__ g2) {
    __shared__ float wl[16], scl[16], shl[16], b2l[1];
    const int tid = threadIdx.x;
    if (tid < 16) { wl[tid] = w2[tid]; scl[tid] = sc[tid]; shl[tid] = sh[tid]; }
    if (tid == 0) b2l[0] = b2[0];
    __syncthreads();
    const int n = blockIdx.x * 256 + tid;
    const ST* r = g1 + (size_t)n * 16;
    float acc = b2l[0];
#pragma unroll
    for (int k = 0; k < 16; k++) {
        float y = fmaxf((float)r[k] * scl[k] + shl[k], 0.f);
        acc += y * wl[k];
    }
    g2[n] = acc;
}

// ---------------- segment softmax + pooling + FC + softmax ----------------
template<typename ST>
__global__ __launch_bounds__(256) void k_pool(const ST* __restrict__ t4,
                                              const float* __restrict__ sc4, const float* __restrict__ sh4,
                                              const float* __restrict__ g2,
                                              const float* __restrict__ gsc2, const float* __restrict__ gsh2,
                                              const float* __restrict__ fcW, const float* __restrict__ fcb,
                                              float* __restrict__ out) {
    __shared__ float fw[32 * NCLS], fbl[NCLS], sc4l[32], sh4l[32];
    const int tid = threadIdx.x;
    for (int i = tid; i < 32 * NCLS; i += 256) fw[i] = fcW[i];
    if (tid < NCLS) fbl[tid] = fcb[tid];
    if (tid < 32) { sc4l[tid] = sc4[tid]; sh4l[tid] = sh4[tid]; }
    __syncthreads();
    const int b = blockIdx.x * 256 + tid;
    const float s2 = gsc2[0], h2 = gsh2[0];
    const int base = b * GSZ;

    float gv[GSZ];
    float m = -1e30f;
#pragma unroll
    for (int i = 0; i < GSZ; i++) {
        float v = fmaxf(g2[base + i] * s2 + h2, 0.f);
        gv[i] = v; m = fmaxf(m, v);
    }
    float ssum = 0.f;
#pragma unroll
    for (int i = 0; i < GSZ; i++) { float e = __expf(gv[i] - m); gv[i] = e; ssum += e; }
    const float inv = 1.0f / ssum;

    float pooled[32];
#pragma unroll
    for (int c = 0; c < 32; c++) pooled[c] = 0.f;
#pragma unroll
    for (int i = 0; i < GSZ; i++) {
        const float a = gv[i] * inv;
        const ST* tr = t4 + (size_t)(base + i) * 32;
#pragma unroll
        for (int c = 0; c < 32; c += 4) {
            float tv[4];
            ldv<ST, 4>(tr + c, tv);
            pooled[c + 0] += a * (tv[0] * sc4l[c + 0] + sh4l[c + 0]);
            pooled[c + 1] += a * (tv[1] * sc4l[c + 1] + sh4l[c + 1]);
            pooled[c + 2] += a * (tv[2] * sc4l[c + 2] + sh4l[c + 2]);
            pooled[c + 3] += a * (tv[3] * sc4l[c + 3] + sh4l[c + 3]);
        }
    }
    float lg[NCLS];
    float mx = -1e30f;
#pragma unroll
    for (int j = 0; j < NCLS; j++) {
        float a = fbl[j];
#pragma unroll
        for (int c = 0; c < 32; c++) a += pooled[c] * fw[c * NCLS + j];
        lg[j] = a; mx = fmaxf(mx, a);
    }
    float es = 0.f;
#pragma unroll
    for (int j = 0; j < NCLS; j++) { float e = __expf(lg[j] - mx); lg[j] = e; es += e; }
    const float iv = 1.0f / es;
#pragma unroll
    for (int j = 0; j < NCLS; j++) out[b * NCLS + j] = lg[j] * iv;
}

// ---------------- templated pipeline (ST = intermediate storage type) ----------------
template<typename ST>
static void run_pipeline(void* const* d_in, float* out, char* base, hipStream_t stream) {
    const float* x    = (const float*)d_in[0];
    const int*   ei   = (const int*)d_in[1];
    const float* W1   = (const float*)d_in[2];
    const float* b1   = (const float*)d_in[3];
    const float* bn1g = (const float*)d_in[4];
    const float* bn1b = (const float*)d_in[5];
    const float* W2   = (const float*)d_in[6];
    const float* b2   = (const float*)d_in[7];
    const float* bn2g = (const float*)d_in[8];
    const float* bn2b = (const float*)d_in[9];
    const float* W3   = (const float*)d_in[10];
    const float* b3   = (const float*)d_in[11];
    const float* bn3g = (const float*)d_in[12];
    const float* bn3b = (const float*)d_in[13];
    const float* W4   = (const float*)d_in[14];
    const float* b4   = (const float*)d_in[15];
    const float* bn4g = (const float*)d_in[16];
    const float* bn4b = (const float*)d_in[17];
    const float* gW1  = (const float*)d_in[18];
    const float* gb1  = (const float*)d_in[19];
    const float* gbn1g = (const float*)d_in[20];
    const float* gbn1b = (const float*)d_in[21];
    const float* gW2  = (const float*)d_in[22];
    const float* gb2  = (const float*)d_in[23];
    const float* gbn2g = (const float*)d_in[24];
    const float* gbn2b = (const float*)d_in[25];
    const float* fcW  = (const float*)d_in[26];
    const float* fcb  = (const float*)d_in[27];

    size_t off_ = 0;
    auto carve = [&](size_t bytes) -> char* {
        char* p = base + off_;
        off_ = (off_ + bytes + 255) & ~(size_t)255;
        return p;
    };
    int*   counts = (int*)carve((size_t)NN * 4);
    float* stats  = (float*)carve(994 * 4);
    const size_t zero_bytes = off_;
    int*   offs   = (int*)carve((size_t)(NN + 1) * 4);
    int*   cursor = (int*)carve((size_t)NN * 4);
    int*   srcs   = (int*)carve((size_t)NE * 4);
    float* dis    = (float*)carve((size_t)NN * 4);
    int*   bsum   = (int*)carve(NSCAN * 4);
    float* pars   = (float*)carve(994 * 4);
    u16*   Wt1h   = (u16*)carve(512 * 128 * 2);
    u16*   Wt1l   = (u16*)carve(512 * 128 * 2);
    u16*   Wt2h   = (u16*)carve(128 * 256 * 2);
    u16*   Wt2l   = (u16*)carve(128 * 256 * 2);
    u16*   Wt3h   = (u16*)carve(256 * 64 * 2);
    u16*   Wt3l   = (u16*)carve(256 * 64 * 2);
    float* g2raw  = (float*)carve((size_t)NN * 4);
    ST*    P      = (ST*)carve((size_t)NN * 128 * sizeof(ST));   // h buffer
    ST*    Q      = (ST*)carve((size_t)NN * 128 * sizeof(ST));   // t buffer (small layers)
    ST*    R      = (ST*)carve((size_t)NN * 256 * sizeof(ST));   // t2 full (N x 256)

    float* S1 = stats;      float* Q1s = S1 + 128;
    float* S2 = Q1s + 128;  float* Q2s = S2 + 256;
    float* S3 = Q2s + 256;  float* Q3s = S3 + 64;
    float* S4 = Q3s + 64;   float* Q4s = S4 + 32;
    float* gS1 = Q4s + 32;  float* gQ1 = gS1 + 16;
    float* gS2 = gQ1 + 16;  float* gQ2 = gS2 + 1;

    float* sc1 = pars;      float* sh1 = sc1 + 128;
    float* sc2 = sh1 + 128; float* sh2 = sc2 + 256;
    float* sc3 = sh2 + 256; float* sh3 = sc3 + 64;
    float* sc4 = sh3 + 64;  float* sh4 = sc4 + 32;
    float* gsc1 = sh4 + 32; float* gsh1 = gsc1 + 16;
    float* gsc2 = gsh1 + 16; float* gsh2 = gsc2 + 1;

    hipMemsetAsync(base, 0, zero_bytes, stream);

    k_hist<<<NE / 256, 256, 0, stream>>>(ei, counts);
    k_scan1<<<NSCAN, 256, 0, stream>>>(counts, bsum);
    k_scan2<<<1, 64, 0, stream>>>(bsum, offs);
    k_scan3<<<NSCAN, 256, 0, stream>>>(counts, bsum, offs);
    k_dis_cursor<<<NN / 256, 256, 0, stream>>>(counts, offs, dis, cursor);
    k_scatter<<<NE / 256, 256, 0, stream>>>(ei, cursor, srcs);
    k_tsplit<<<(512 * 128 + 255) / 256, 256, 0, stream>>>(W1, Wt1h, Wt1l, 512, 128);
    k_tsplit<<<(128 * 256 + 255) / 256, 256, 0, stream>>>(W2, Wt2h, Wt2l, 128, 256);
    k_tsplit<<<(256 * 64 + 255) / 256, 256, 0, stream>>>(W3, Wt3h, Wt3l, 256, 64);

    // layer 1: h1 = x @ W1 -> P (N x 128); t1 -> Q
    k_gemm<128, 128, 2, float, ST, false><<<dim3(1, NN / 128), 256, 0, stream>>>(
        x, Wt1h, Wt1l, P, 512, 128, nullptr, nullptr);
    k_agg<128, 2, ST><<<1024, 256, 0, stream>>>(P, Q, b1, offs, srcs, dis, S1, Q1s, 128, 128);
    k_bnpar<<<1, 256, 0, stream>>>(S1, Q1s, bn1g, bn1b, sc1, sh1, 128);

    // layer 2 (channel-split in halves of 128): h2x = bn(t1) @ W2[:,half] -> P; t2 -> R (stride 256)
    k_gemm<128, 128, 2, ST, ST, true><<<dim3(1, NN / 128), 256, 0, stream>>>(
        Q, Wt2h, Wt2l, P, 128, 128, sc1, sh1);
    k_agg<128, 2, ST><<<1024, 256, 0, stream>>>(P, R, b2, offs, srcs, dis, S2, Q2s, 128, 256);
    k_gemm<128, 128, 2, ST, ST, true><<<dim3(1, NN / 128), 256, 0, stream>>>(
        Q, Wt2h + 128 * 128, Wt2l + 128 * 128, P, 128, 128, sc1, sh1);
    k_agg<128, 2, ST><<<1024, 256, 0, stream>>>(P, R + 128, b2 + 128, offs, srcs, dis,
                                                S2 + 128, Q2s + 128, 128, 256);
    k_bnpar<<<1, 256, 0, stream>>>(S2, Q2s, bn2g, bn2b, sc2, sh2, 256);

    // layer 3: h3 = bn(t2) @ W3 -> P (N x 64); t3 -> Q
    k_gemm<256, 64, 1, ST, ST, true><<<dim3(1, NN / 256), 256, 0, stream>>>(
        R, Wt3h, Wt3l, P, 256, 64, sc2, sh2);
    k_agg<64, 1, ST><<<1024, 256, 0, stream>>>(P, Q, b3, offs, srcs, dis, S3, Q3s, 64, 64);
    k_bnpar<<<1, 256, 0, stream>>>(S3, Q3s, bn3g, bn3b, sc3, sh3, 64);

    // layer 4: h4 = bn(t3) @ W4 -> P (N x 32); t4 -> Q
    k_smm<64, 32, false, ST><<<NN / 256, 256, 0, stream>>>(Q, W4, nullptr, P, sc3, sh3);
    k_agg<32, 1, ST><<<1024, 256, 0, stream>>>(P, Q, b4, offs, srcs, dis, S4, Q4s, 32, 32);
    k_bnpar<<<1, 256, 0, stream>>>(S4, Q4s, bn4g, bn4b, sc4, sh4, 32);

    // gate 1: g1 = bn4(t4) @ gW1 + gb1 -> P (N x 16)
    k_smm<32, 16, true, ST><<<NN / 256, 256, 0, stream>>>(Q, gW1, gb1, P, sc4, sh4);
    k_stats16<16, ST><<<NSCAN, 256, 0, stream>>>(P, gS1, gQ1);
    k_bnpar<<<1, 256, 0, stream>>>(gS1, gQ1, gbn1g, gbn1b, gsc1, gsh1, 16);

    // gate 2: g2 = relu(bn(g1)) @ gW2 + gb2 -> g2raw (N, fp32)
    k_gate2<ST><<<NN / 256, 256, 0, stream>>>(P, gsc1, gsh1, gW2, gb2, g2raw);
    k_stats1<<<NSCAN, 256, 0, stream>>>(g2raw, gS2, gQ2);
    k_bnpar<<<1, 256, 0, stream>>>(gS2, gQ2, gbn2g, gbn2b, gsc2, gsh2, 1);

    // pooling + FC + softmax
    k_pool<ST><<<NBATCH / 256, 256, 0, stream>>>(Q, sc4, sh4, g2raw, gsc2, gsh2, fcW, fcb, out);
}

// ---------------- host ----------------
extern "C" void kernel_launch(void* const* d_in, const int* in_sizes, int n_in,
                              void* d_out, int out_size, void* d_ws, size_t ws_size,
                              hipStream_t stream) {
    (void)in_sizes; (void)n_in; (void)out_size;
    float* out = (float*)d_out;
    char* base = (char*)d_ws;
    // fp32 path needs ~241.5 MB (aux ~6.5 + P 58.7 + Q 58.7 + R 117.4); fp16 path ~124 MB.
    const size_t need32 = 250ull * 1024 * 1024;
    if (ws_size >= need32) {
        run_pipeline<float>(d_in, out, base, stream);
    } else {
        run_pipeline<_Float16>(d_in, out, base, stream);
    }
}

// Round 5
// 1164.930 us; speedup vs baseline: 1.3518x; 1.3518x over previous
//
#include <hip/hip_runtime.h>

#define NN 114688      // nodes
#define NE 917504      // edges
#define NBATCH 8192    // graphs
#define GSZ 14         // nodes per graph
#define NCLS 10
#define EPSB 1e-5f
#define NSCAN 112      // NN / 1024

typedef unsigned short u16;
typedef short bf16x8 __attribute__((ext_vector_type(8)));
typedef float f32x4 __attribute__((ext_vector_type(4)));
typedef _Float16 h8t __attribute__((ext_vector_type(8)));

__device__ __forceinline__ float bf2f(u16 u) {
    union { unsigned int i; float f; } v; v.i = ((unsigned int)u) << 16; return v.f;
}
__device__ __forceinline__ u16 f2bf(float f) {
    union { float f; unsigned int i; } v; v.f = f;
    unsigned int i = v.i;
    unsigned int r = i + 0x7FFFu + ((i >> 16) & 1u);   // RNE
    return (u16)(r >> 16);
}

// ---------------- graph preprocessing ----------------
__global__ __launch_bounds__(256) void k_hist(const int* __restrict__ ei, int* __restrict__ counts) {
    int e = blockIdx.x * 256 + threadIdx.x;
    atomicAdd(&counts[ei[NE + e]], 1);
}

__global__ __launch_bounds__(256) void k_scan1(const int* __restrict__ counts, int* __restrict__ bsum) {
    __shared__ int red[256];
    int tid = threadIdx.x;
    int base = blockIdx.x * 1024 + tid * 4;
    int s = counts[base] + counts[base + 1] + counts[base + 2] + counts[base + 3];
    red[tid] = s; __syncthreads();
    for (int o = 128; o > 0; o >>= 1) {
        if (tid < o) red[tid] += red[tid + o];
        __syncthreads();
    }
    if (tid == 0) bsum[blockIdx.x] = red[0];
}

__global__ void k_scan2(int* bsum, int* offs) {
    if (threadIdx.x == 0) {
        int run = 0;
        for (int i = 0; i < NSCAN; i++) { int t = bsum[i]; bsum[i] = run; run += t; }
        offs[NN] = run;
    }
}

__global__ __launch_bounds__(256) void k_scan3(const int* __restrict__ counts, const int* __restrict__ bsum,
                                               int* __restrict__ offs) {
    __shared__ int ss[256];
    int tid = threadIdx.x;
    int base = blockIdx.x * 1024 + tid * 4;
    int v0 = counts[base], v1 = counts[base + 1], v2 = counts[base + 2], v3 = counts[base + 3];
    int ts = v0 + v1 + v2 + v3;
    ss[tid] = ts; __syncthreads();
    for (int o = 1; o < 256; o <<= 1) {
        int add = (tid >= o) ? ss[tid - o] : 0;
        __syncthreads();
        ss[tid] += add;
        __syncthreads();
    }
    int excl = ss[tid] - ts + bsum[blockIdx.x];
    offs[base] = excl;
    offs[base + 1] = excl + v0;
    offs[base + 2] = excl + v0 + v1;
    offs[base + 3] = excl + v0 + v1 + v2;
}

__global__ __launch_bounds__(256) void k_dis_cursor(const int* __restrict__ counts, const int* __restrict__ offs,
                                                    float* __restrict__ dis, int* __restrict__ cursor) {
    int n = blockIdx.x * 256 + threadIdx.x;
    dis[n] = rsqrtf((float)counts[n] + 1.0f);
    cursor[n] = offs[n];
}

// scatter edges into CSR; also materialize per-edge source weight sd = dis[src]
__global__ __launch_bounds__(256) void k_scatter(const int* __restrict__ ei, int* __restrict__ cursor,
                                                 int* __restrict__ srcs, float* __restrict__ sd,
                                                 const float* __restrict__ dis) {
    int e = blockIdx.x * 256 + threadIdx.x;
    int d = ei[NE + e], s = ei[e];
    int p = atomicAdd(&cursor[d], 1);
    srcs[p] = s;
    sd[p] = dis[s];
}

// transpose + hi/lo-split fp32 W[K,F] -> bf16 Wh/Wl [F,K]  (Markidis split)
__global__ __launch_bounds__(256) void k_tsplit(const float* __restrict__ Wsrc,
                                                u16* __restrict__ Wh, u16* __restrict__ Wl,
                                                int K, int F) {
    int i = blockIdx.x * 256 + threadIdx.x;
    if (i < K * F) {
        int k = i / F, f = i % F;
        float w = Wsrc[i];
        u16 h = f2bf(w);
        float r = w - bf2f(h);
        Wh[f * K + k] = h;
        Wl[f * K + k] = f2bf(r);
    }
}

// ---------------- split MFMA GEMM: C = affine(A) @ W, fp32-grade via bf16x3 ----------------
// A fp32, optional per-channel affine. W pre-split bf16 hi/lo [Fout][K]. C stored fp16.
template<int BM, int BN, int WCOLS, bool AFF>
__global__ __launch_bounds__(256) void k_gemm(
    const float* __restrict__ A, const u16* __restrict__ Wh, const u16* __restrict__ Wl,
    _Float16* __restrict__ C, const int K, const int Fout,
    const float* __restrict__ sc, const float* __restrict__ sh)
{
    constexpr int AST = 40;                // 32 + 8 pad
    __shared__ u16 Ah[BM][AST], Al[BM][AST];
    __shared__ u16 Bh[BN][AST], Bl[BN][AST];
    __shared__ float scs[AFF ? 256 : 1], shs[AFF ? 256 : 1];

    const int tid = threadIdx.x;
    const int row0 = blockIdx.y * BM;
    const int col0 = blockIdx.x * BN;

    if constexpr (AFF) {
        for (int i = tid; i < K; i += 256) { scs[i] = sc[i]; shs[i] = sh[i]; }
    }

    const int wave = tid >> 6, lane = tid & 63;
    const int mb = (wave / WCOLS) * 64;
    const int nb = (wave % WCOLS) * 64;
    const int lm = lane & 15;
    const int lk = (lane >> 4) * 8;

    f32x4 acc[4][4];
#pragma unroll
    for (int i = 0; i < 4; i++)
#pragma unroll
        for (int j = 0; j < 4; j++)
#pragma unroll
            for (int r = 0; r < 4; r++) acc[i][j][r] = 0.f;

    const int stg_r = tid >> 3;        // 0..31
    const int stg_c = (tid & 7) * 4;   // 0,4..28

    for (int k0 = 0; k0 < K; k0 += 32) {
        __syncthreads();
#pragma unroll
        for (int p = 0; p < BM / 32; p++) {
            const int r = p * 32 + stg_r;
            const float4 v = *(const float4*)(A + (size_t)(row0 + r) * K + k0 + stg_c);
            float y[4] = {v.x, v.y, v.z, v.w};
            ushort4 hv, lv;
#pragma unroll
            for (int q = 0; q < 4; q++) {
                float yy = y[q];
                if constexpr (AFF) yy = yy * scs[k0 + stg_c + q] + shs[k0 + stg_c + q];
                u16 h = f2bf(yy);
                float rm = yy - bf2f(h);
                ((u16*)&hv)[q] = h;
                ((u16*)&lv)[q] = f2bf(rm);
            }
            *(ushort4*)&Ah[r][stg_c] = hv;
            *(ushort4*)&Al[r][stg_c] = lv;
        }
#pragma unroll
        for (int p = 0; p < BN / 32; p++) {
            const int n = p * 32 + stg_r;
            *(ushort4*)&Bh[n][stg_c] = *(const ushort4*)(Wh + (size_t)(col0 + n) * K + k0 + stg_c);
            *(ushort4*)&Bl[n][stg_c] = *(const ushort4*)(Wl + (size_t)(col0 + n) * K + k0 + stg_c);
        }
        __syncthreads();

        bf16x8 ah[4], al[4], bh[4], bl[4];
#pragma unroll
        for (int mi = 0; mi < 4; mi++) {
            ah[mi] = *(const bf16x8*)&Ah[mb + mi * 16 + lm][lk];
            al[mi] = *(const bf16x8*)&Al[mb + mi * 16 + lm][lk];
        }
#pragma unroll
        for (int ni = 0; ni < 4; ni++) {
            bh[ni] = *(const bf16x8*)&Bh[nb + ni * 16 + lm][lk];
            bl[ni] = *(const bf16x8*)&Bl[nb + ni * 16 + lm][lk];
        }
#pragma unroll
        for (int mi = 0; mi < 4; mi++)
#pragma unroll
            for (int ni = 0; ni < 4; ni++) {
                acc[mi][ni] = __builtin_amdgcn_mfma_f32_16x16x32_bf16(al[mi], bh[ni], acc[mi][ni], 0, 0, 0);
                acc[mi][ni] = __builtin_amdgcn_mfma_f32_16x16x32_bf16(ah[mi], bl[ni], acc[mi][ni], 0, 0, 0);
                acc[mi][ni] = __builtin_amdgcn_mfma_f32_16x16x32_bf16(ah[mi], bh[ni], acc[mi][ni], 0, 0, 0);
            }
    }

    const int rb = row0 + mb + (lane >> 4) * 4;
    const int cb = col0 + nb + lm;
#pragma unroll
    for (int mi = 0; mi < 4; mi++)
#pragma unroll
        for (int ni = 0; ni < 4; ni++)
#pragma unroll
            for (int r = 0; r < 4; r++)
                C[(size_t)(rb + mi * 16 + r) * Fout + cb + ni * 16] = (_Float16)acc[mi][ni][r];
}

// ---------------- aggregation: t = relu(dn*sum(sd_e*h_s) + dn^2*h_n + b), fused BN stats --------
// h fp16 (stride CH), t fp32 (stride ostr). Edge-parallel: NSUB sub-wavelets each take one edge,
// 8 ch/lane (16B); butterfly shfl_xor merges partials. Stats on stored (fp32, exact) values.
template<int CH>
__global__ __launch_bounds__(256) void k_agg(
    const _Float16* __restrict__ h, float* __restrict__ t, const float* __restrict__ bias,
    const int* __restrict__ off, const int* __restrict__ srcs, const float* __restrict__ sd,
    const float* __restrict__ dis, float* __restrict__ statS, float* __restrict__ statQ,
    const int ostr)
{
    constexpr int ECH = 8;             // channels per lane (16B fp16)
    constexpr int LPG = CH / ECH;      // lanes per edge-group
    constexpr int NSUB = 64 / LPG;     // edges in flight per wave
    __shared__ float redS[CH], redQ[CH];
    const int tid = threadIdx.x;
    for (int i = tid; i < CH; i += 256) { redS[i] = 0.f; redQ[i] = 0.f; }
    __syncthreads();

    const int lane = tid & 63;
    const int sub = lane / LPG;
    const int c = (lane % LPG) * ECH;
    const int wid = (blockIdx.x * 256 + tid) >> 6;
    const int nw = (gridDim.x * 256) >> 6;

    float bs[ECH], bq[ECH], bv[ECH];
#pragma unroll
    for (int v = 0; v < ECH; v++) { bs[v] = 0.f; bq[v] = 0.f; bv[v] = bias[c + v]; }

    for (int n = wid; n < NN; n += nw) {
        const int p0 = off[n], p1 = off[n + 1];
        float a[ECH];
#pragma unroll
        for (int v = 0; v < ECH; v++) a[v] = 0.f;

        int p = p0 + sub;
        int s = 0; float w = 0.f;
        if (p < p1) { s = srcs[p]; w = sd[p]; }      // index+weight load in parallel
        while (p < p1) {
            const int pn = p + NSUB;
            int s2 = 0; float w2 = 0.f;
            if (pn < p1) { s2 = srcs[pn]; w2 = sd[pn]; }   // prefetch next edge
            h8t hv = *(const h8t*)(h + (size_t)s * CH + c);
#pragma unroll
            for (int v = 0; v < ECH; v++) a[v] += w * (float)hv[v];
            s = s2; w = w2; p = pn;
        }
        // merge edge-group partials: butterfly over strides LPG..32
#pragma unroll
        for (int o = LPG; o < 64; o <<= 1) {
#pragma unroll
            for (int v = 0; v < ECH; v++) a[v] += __shfl_xor(a[v], o);
        }
        if (sub == 0) {
            const float dn = dis[n];
            const float dn2 = dn * dn;
            h8t hn = *(const h8t*)(h + (size_t)n * CH + c);
            float o8[ECH];
#pragma unroll
            for (int v = 0; v < ECH; v++) {
                float ov = fmaxf(dn * a[v] + dn2 * (float)hn[v] + bv[v], 0.f);
                o8[v] = ov;
                bs[v] += ov; bq[v] += ov * ov;
            }
            float* tr = t + (size_t)n * ostr + c;
            float4 w0; w0.x = o8[0]; w0.y = o8[1]; w0.z = o8[2]; w0.w = o8[3];
            float4 w1; w1.x = o8[4]; w1.y = o8[5]; w1.z = o8[6]; w1.w = o8[7];
            *(float4*)tr = w0;
            *(float4*)(tr + 4) = w1;
        }
    }
    if (sub == 0) {
#pragma unroll
        for (int v = 0; v < ECH; v++) { atomicAdd(&redS[c + v], bs[v]); atomicAdd(&redQ[c + v], bq[v]); }
    }
    __syncthreads();
    for (int i = tid; i < CH; i += 256) { atomicAdd(&statS[i], redS[i]); atomicAdd(&statQ[i], redQ[i]); }
}

// ---------------- BN stats -> scale/shift ----------------
__global__ void k_bnpar(const float* __restrict__ S, const float* __restrict__ Q,
                        const float* __restrict__ g, const float* __restrict__ b,
                        float* __restrict__ sc, float* __restrict__ sh, int F) {
    int c = threadIdx.x;
    if (c >= F) return;
    const float invn = 1.0f / (float)NN;
    float mean = S[c] * invn;
    float var = Q[c] * invn - mean * mean;
    float s = g[c] * rsqrtf(fmaxf(var, 0.f) + EPSB);
    sc[c] = s;
    sh[c] = b[c] - mean * s;
}

// ---------------- small dense layer: C[N,F] = affine(A)[N,K] @ W[K,F] (+bias) ----------------
// A fp32, C fp16, fp32 compute.
template<int K, int F, bool BIAS>
__global__ __launch_bounds__(256) void k_smm(
    const float* __restrict__ A, const float* __restrict__ Wf, const float* __restrict__ bias,
    _Float16* __restrict__ C, const float* __restrict__ sc, const float* __restrict__ sh)
{
    __shared__ float Wl[K * F];
    __shared__ float scl[K], shl[K], bl[F];
    const int tid = threadIdx.x;
    for (int i = tid; i < K * F; i += 256) Wl[i] = Wf[i];
    if (tid < K) { scl[tid] = sc[tid]; shl[tid] = sh[tid]; }
    if (tid < F) {
        bl[tid] = 0.f;
        if constexpr (BIAS) bl[tid] = bias[tid];
    }
    __syncthreads();
    const int n = blockIdx.x * 256 + tid;
    float acc[F];
#pragma unroll
    for (int f = 0; f < F; f++) acc[f] = bl[f];
    const float* ar = A + (size_t)n * K;
    for (int k = 0; k < K; k += 4) {
        float4 av = *(const float4*)(ar + k);
        float y0 = av.x * scl[k] + shl[k];
        float y1 = av.y * scl[k + 1] + shl[k + 1];
        float y2 = av.z * scl[k + 2] + shl[k + 2];
        float y3 = av.w * scl[k + 3] + shl[k + 3];
#pragma unroll
        for (int f = 0; f < F; f += 4) {
            float4 w0 = *(const float4*)&Wl[k * F + f];
            float4 w1 = *(const float4*)&Wl[(k + 1) * F + f];
            float4 w2 = *(const float4*)&Wl[(k + 2) * F + f];
            float4 w3 = *(const float4*)&Wl[(k + 3) * F + f];
            acc[f + 0] += y0 * w0.x + y1 * w1.x + y2 * w2.x + y3 * w3.x;
            acc[f + 1] += y0 * w0.y + y1 * w1.y + y2 * w2.y + y3 * w3.y;
            acc[f + 2] += y0 * w0.z + y1 * w1.z + y2 * w2.z + y3 * w3.z;
            acc[f + 3] += y0 * w0.w + y1 * w1.w + y2 * w2.w + y3 * w3.w;
        }
    }
    _Float16* cr = C + (size_t)n * F;
#pragma unroll
    for (int f = 0; f < F; f++) cr[f] = (_Float16)acc[f];
}

// ---------------- per-channel stats over [NN, F] fp16 ----------------
template<int F>
__global__ __launch_bounds__(256) void k_stats16(const _Float16* __restrict__ A,
                                                 float* __restrict__ S, float* __restrict__ Q) {
    __shared__ float redS[F], redQ[F];
    const int tid = threadIdx.x;
    for (int i = tid; i < F; i += 256) { redS[i] = 0.f; redQ[i] = 0.f; }
    __syncthreads();
    const int g = blockIdx.x * 256 + tid;
    const int c = g % F;
    const int step = (gridDim.x * 256) / F;
    float s = 0.f, q = 0.f;
    for (int r = g / F; r < NN; r += step) {
        float v = (float)A[(size_t)r * F + c];
        s += v; q += v * v;
    }
    atomicAdd(&redS[c], s); atomicAdd(&redQ[c], q);
    __syncthreads();
    for (int i = tid; i < F; i += 256) { atomicAdd(&S[i], redS[i]); atomicAdd(&Q[i], redQ[i]); }
}

// stats over fp32 [NN] vector
__global__ __launch_bounds__(256) void k_stats1(const float* __restrict__ A,
                                                float* __restrict__ S, float* __restrict__ Q) {
    __shared__ float redS[1], redQ[1];
    const int tid = threadIdx.x;
    if (tid == 0) { redS[0] = 0.f; redQ[0] = 0.f; }
    __syncthreads();
    const int g = blockIdx.x * 256 + tid;
    const int step = gridDim.x * 256;
    float s = 0.f, q = 0.f;
    for (int r = g; r < NN; r += step) {
        float v = A[r];
        s += v; q += v * v;
    }
    atomicAdd(&redS[0], s); atomicAdd(&redQ[0], q);
    __syncthreads();
    if (tid == 0) { atomicAdd(&S[0], redS[0]); atomicAdd(&Q[0], redQ[0]); }
}

// ---------------- gate layer 2: g2 = relu(bn1(g1)) @ gW2 + gb2 ----------------
__global__ __launch_bounds__(256) void k_gate2(const _Float16* __restrict__ g1,
                                               const float* __restrict__ sc, const float* __restrict__ sh,
                                               const float* __restrict__ w2, const float* __restrict__ b2,
                                               float* __restrict__ g2) {
    __shared__ float wl[16], scl[16], shl[16], b2l[1];
    const int tid = threadIdx.x;
    if (tid < 16) { wl[tid] = w2[tid]; scl[tid] = sc[tid]; shl[tid] = sh[tid]; }
    if (tid == 0) b2l[0] = b2[0];
    __syncthreads();
    const int n = blockIdx.x * 256 + tid;
    const _Float16* r = g1 + (size_t)n * 16;
    float acc = b2l[0];
#pragma unroll
    for (int k = 0; k < 16; k++) {
        float y = fmaxf((float)r[k] * scl[k] + shl[k], 0.f);
        acc += y * wl[k];
    }
    g2[n] = acc;
}

// ---------------- segment softmax + pooling + FC + softmax ----------------
__global__ __launch_bounds__(256) void k_pool(const float* __restrict__ t4,
                                              const float* __restrict__ sc4, const float* __restrict__ sh4,
                                              const float* __restrict__ g2,
                                              const float* __restrict__ gsc2, const float* __restrict__ gsh2,
                                              const float* __restrict__ fcW, const float* __restrict__ fcb,
                                              float* __restrict__ out) {
    __shared__ float fw[32 * NCLS], fbl[NCLS], sc4l[32], sh4l[32];
    const int tid = threadIdx.x;
    for (int i = tid; i < 32 * NCLS; i += 256) fw[i] = fcW[i];
    if (tid < NCLS) fbl[tid] = fcb[tid];
    if (tid < 32) { sc4l[tid] = sc4[tid]; sh4l[tid] = sh4[tid]; }
    __syncthreads();
    const int b = blockIdx.x * 256 + tid;
    const float s2 = gsc2[0], h2 = gsh2[0];
    const int base = b * GSZ;

    float gv[GSZ];
    float m = -1e30f;
#pragma unroll
    for (int i = 0; i < GSZ; i++) {
        float v = fmaxf(g2[base + i] * s2 + h2, 0.f);
        gv[i] = v; m = fmaxf(m, v);
    }
    float ssum = 0.f;
#pragma unroll
    for (int i = 0; i < GSZ; i++) { float e = __expf(gv[i] - m); gv[i] = e; ssum += e; }
    const float inv = 1.0f / ssum;

    float pooled[32];
#pragma unroll
    for (int c = 0; c < 32; c++) pooled[c] = 0.f;
#pragma unroll
    for (int i = 0; i < GSZ; i++) {
        const float a = gv[i] * inv;
        const float* tr = t4 + (size_t)(base + i) * 32;
#pragma unroll
        for (int c = 0; c < 32; c += 4) {
            float4 tv = *(const float4*)(tr + c);
            pooled[c + 0] += a * (tv.x * sc4l[c + 0] + sh4l[c + 0]);
            pooled[c + 1] += a * (tv.y * sc4l[c + 1] + sh4l[c + 1]);
            pooled[c + 2] += a * (tv.z * sc4l[c + 2] + sh4l[c + 2]);
            pooled[c + 3] += a * (tv.w * sc4l[c + 3] + sh4l[c + 3]);
        }
    }
    float lg[NCLS];
    float mx = -1e30f;
#pragma unroll
    for (int j = 0; j < NCLS; j++) {
        float a = fbl[j];
#pragma unroll
        for (int c = 0; c < 32; c++) a += pooled[c] * fw[c * NCLS + j];
        lg[j] = a; mx = fmaxf(mx, a);
    }
    float es = 0.f;
#pragma unroll
    for (int j = 0; j < NCLS; j++) { float e = __expf(lg[j] - mx); lg[j] = e; es += e; }
    const float iv = 1.0f / es;
#pragma unroll
    for (int j = 0; j < NCLS; j++) out[b * NCLS + j] = lg[j] * iv;
}

// ---------------- host ----------------
extern "C" void kernel_launch(void* const* d_in, const int* in_sizes, int n_in,
                              void* d_out, int out_size, void* d_ws, size_t ws_size,
                              hipStream_t stream) {
    (void)in_sizes; (void)n_in; (void)out_size; (void)ws_size;
    const float* x    = (const float*)d_in[0];
    const int*   ei   = (const int*)d_in[1];
    const float* W1   = (const float*)d_in[2];
    const float* b1   = (const float*)d_in[3];
    const float* bn1g = (const float*)d_in[4];
    const float* bn1b = (const float*)d_in[5];
    const float* W2   = (const float*)d_in[6];
    const float* b2   = (const float*)d_in[7];
    const float* bn2g = (const float*)d_in[8];
    const float* bn2b = (const float*)d_in[9];
    const float* W3   = (const float*)d_in[10];
    const float* b3   = (const float*)d_in[11];
    const float* bn3g = (const float*)d_in[12];
    const float* bn3b = (const float*)d_in[13];
    const float* W4   = (const float*)d_in[14];
    const float* b4   = (const float*)d_in[15];
    const float* bn4g = (const float*)d_in[16];
    const float* bn4b = (const float*)d_in[17];
    const float* gW1  = (const float*)d_in[18];
    const float* gb1  = (const float*)d_in[19];
    const float* gbn1g = (const float*)d_in[20];
    const float* gbn1b = (const float*)d_in[21];
    const float* gW2  = (const float*)d_in[22];
    const float* gb2  = (const float*)d_in[23];
    const float* gbn2g = (const float*)d_in[24];
    const float* gbn2b = (const float*)d_in[25];
    const float* fcW  = (const float*)d_in[26];
    const float* fcb  = (const float*)d_in[27];
    float* out = (float*)d_out;

    char* base = (char*)d_ws;
    size_t off_ = 0;
    auto carve = [&](size_t bytes) -> char* {
        char* p = base + off_;
        off_ = (off_ + bytes + 255) & ~(size_t)255;
        return p;
    };
    int*   counts = (int*)carve((size_t)NN * 4);
    float* stats  = (float*)carve(994 * 4);
    const size_t zero_bytes = off_;
    int*   offs   = (int*)carve((size_t)(NN + 1) * 4);
    int*   cursor = (int*)carve((size_t)NN * 4);
    int*   srcs   = (int*)carve((size_t)NE * 4);
    float* sd     = (float*)carve((size_t)NE * 4);
    float* dis    = (float*)carve((size_t)NN * 4);
    int*   bsum   = (int*)carve(NSCAN * 4);
    float* pars   = (float*)carve(994 * 4);
    u16*   Wt1h   = (u16*)carve(512 * 128 * 2);
    u16*   Wt1l   = (u16*)carve(512 * 128 * 2);
    u16*   Wt2h   = (u16*)carve(128 * 256 * 2);
    u16*   Wt2l   = (u16*)carve(128 * 256 * 2);
    u16*   Wt3h   = (u16*)carve(256 * 64 * 2);
    u16*   Wt3l   = (u16*)carve(256 * 64 * 2);
    float* g2raw  = (float*)carve((size_t)NN * 4);
    _Float16* P   = (_Float16*)carve((size_t)NN * 128 * 2);   // h buffer (fp16)
    float*    Q   = (float*)carve((size_t)NN * 128 * 4);      // t buffer (fp32, small layers)
    float*    R   = (float*)carve((size_t)NN * 256 * 4);      // t2 full (fp32, N x 256)
    // total ~216 MB (< proven-available 250 MB)

    float* S1 = stats;      float* Q1s = S1 + 128;
    float* S2 = Q1s + 128;  float* Q2s = S2 + 256;
    float* S3 = Q2s + 256;  float* Q3s = S3 + 64;
    float* S4 = Q3s + 64;   float* Q4s = S4 + 32;
    float* gS1 = Q4s + 32;  float* gQ1 = gS1 + 16;
    float* gS2 = gQ1 + 16;  float* gQ2 = gS2 + 1;

    float* sc1 = pars;      float* sh1 = sc1 + 128;
    float* sc2 = sh1 + 128; float* sh2 = sc2 + 256;
    float* sc3 = sh2 + 256; float* sh3 = sc3 + 64;
    float* sc4 = sh3 + 64;  float* sh4 = sc4 + 32;
    float* gsc1 = sh4 + 32; float* gsh1 = gsc1 + 16;
    float* gsc2 = gsh1 + 16; float* gsh2 = gsc2 + 1;

    hipMemsetAsync(d_ws, 0, zero_bytes, stream);

    k_hist<<<NE / 256, 256, 0, stream>>>(ei, counts);
    k_scan1<<<NSCAN, 256, 0, stream>>>(counts, bsum);
    k_scan2<<<1, 64, 0, stream>>>(bsum, offs);
    k_scan3<<<NSCAN, 256, 0, stream>>>(counts, bsum, offs);
    k_dis_cursor<<<NN / 256, 256, 0, stream>>>(counts, offs, dis, cursor);
    k_scatter<<<NE / 256, 256, 0, stream>>>(ei, cursor, srcs, sd, dis);
    k_tsplit<<<(512 * 128 + 255) / 256, 256, 0, stream>>>(W1, Wt1h, Wt1l, 512, 128);
    k_tsplit<<<(128 * 256 + 255) / 256, 256, 0, stream>>>(W2, Wt2h, Wt2l, 128, 256);
    k_tsplit<<<(256 * 64 + 255) / 256, 256, 0, stream>>>(W3, Wt3h, Wt3l, 256, 64);

    // layer 1: h1 = x @ W1 -> P (N x 128 fp16); t1 -> Q (fp32)
    k_gemm<128, 128, 2, false><<<dim3(1, NN / 128), 256, 0, stream>>>(
        x, Wt1h, Wt1l, P, 512, 128, nullptr, nullptr);
    k_agg<128><<<2048, 256, 0, stream>>>(P, Q, b1, offs, srcs, sd, dis, S1, Q1s, 128);
    k_bnpar<<<1, 256, 0, stream>>>(S1, Q1s, bn1g, bn1b, sc1, sh1, 128);

    // layer 2 (channel-split halves of 128): h2x = bn(t1) @ W2[:,half] -> P; t2 -> R (stride 256)
    k_gemm<128, 128, 2, true><<<dim3(1, NN / 128), 256, 0, stream>>>(
        Q, Wt2h, Wt2l, P, 128, 128, sc1, sh1);
    k_agg<128><<<2048, 256, 0, stream>>>(P, R, b2, offs, srcs, sd, dis, S2, Q2s, 256);
    k_gemm<128, 128, 2, true><<<dim3(1, NN / 128), 256, 0, stream>>>(
        Q, Wt2h + 128 * 128, Wt2l + 128 * 128, P, 128, 128, sc1, sh1);
    k_agg<128><<<2048, 256, 0, stream>>>(P, R + 128, b2 + 128, offs, srcs, sd, dis,
                                         S2 + 128, Q2s + 128, 256);
    k_bnpar<<<1, 256, 0, stream>>>(S2, Q2s, bn2g, bn2b, sc2, sh2, 256);

    // layer 3: h3 = bn(t2) @ W3 -> P (N x 64 fp16); t3 -> Q
    k_gemm<256, 64, 1, true><<<dim3(1, NN / 256), 256, 0, stream>>>(
        R, Wt3h, Wt3l, P, 256, 64, sc2, sh2);
    k_agg<64><<<2048, 256, 0, stream>>>(P, Q, b3, offs, srcs, sd, dis, S3, Q3s, 64);
    k_bnpar<<<1, 256, 0, stream>>>(S3, Q3s, bn3g, bn3b, sc3, sh3, 64);

    // layer 4: h4 = bn(t3) @ W4 -> P (N x 32 fp16); t4 -> Q
    k_smm<64, 32, false><<<NN / 256, 256, 0, stream>>>(Q, W4, nullptr, P, sc3, sh3);
    k_agg<32><<<2048, 256, 0, stream>>>(P, Q, b4, offs, srcs, sd, dis, S4, Q4s, 32);
    k_bnpar<<<1, 256, 0, stream>>>(S4, Q4s, bn4g, bn4b, sc4, sh4, 32);

    // gate 1: g1 = bn4(t4) @ gW1 + gb1 -> P (N x 16 fp16)
    k_smm<32, 16, true><<<NN / 256, 256, 0, stream>>>(Q, gW1, gb1, P, sc4, sh4);
    k_stats16<16><<<NSCAN, 256, 0, stream>>>(P, gS1, gQ1);
    k_bnpar<<<1, 256, 0, stream>>>(gS1, gQ1, gbn1g, gbn1b, gsc1, gsh1, 16);

    // gate 2: g2 = relu(bn(g1)) @ gW2 + gb2 -> g2raw (N, fp32)
    k_gate2<<<NN / 256, 256, 0, stream>>>(P, gsc1, gsh1, gW2, gb2, g2raw);
    k_stats1<<<NSCAN, 256, 0, stream>>>(g2raw, gS2, gQ2);
    k_bnpar<<<1, 256, 0, stream>>>(gS2, gQ2, gbn2g, gbn2b, gsc2, gsh2, 1);

    // pooling + FC + softmax
    k_pool<<<NBATCH / 256, 256, 0, stream>>>(Q, sc4, sh4, g2raw, gsc2, gsh2, fcW, fcb, out);
}